// Round 8
// baseline (1828.882 us; speedup 1.0000x reference)
//
#include <hip/hip_runtime.h>
#include <math.h>

// TransformersLSTM: T=512, I=512, H=1024, L=512, O=1.
// Split-grid persistent kernel: blocks 0..127 encoder, 128..255 decoder.
// R20 = R12 structure + ATOMIC-RMW DATA PLANE (stale-L2-dwell theory).
// Evidence: discovery ~2.6us invariant to poller count (R13/R18), producer
// path (R15), serialization (R16/R17), and load scope bits (R19). The one
// mechanism invariant to all: consumer's XCD-local L2 serving a STALE copy of
// the frontier line until eviction (~2.6us set-churn dwell). Loads can be
// stale on CDNA4; device-scope atomic RMWs execute AT the coherence point and
// cannot read stale lines. Change: ALL discovery reads (polls + speculative
// samples) become returning global_atomic_or(addr, 0); publication becomes
// fire-and-forget global_atomic_swap. Poison backbone unchanged (write-once
// buffers: a stale read can only be poison) => soundness identical to R12.
// Retry rounds throttled with s_sleep(1) to bound per-address atomic
// serialization (~128 pollers/address at the LLC slice).

#define T_STEPS 512
#define ENC_BLK 128
#define NBLK    256
#define NTHR    512
#define APOLL_LIMIT 8000u

typedef float fv4 __attribute__((ext_vector_type(4)));

__device__ __forceinline__ float sigf(float x) { return 1.0f / (1.0f + expf(-x)); }

// coherence-point read of one dword: atomic OR with 0 returns the LLC value.
__device__ __forceinline__ unsigned ld_coh(unsigned* p) {
  return __hip_atomic_fetch_or(p, 0u, __ATOMIC_RELAXED, __HIP_MEMORY_SCOPE_AGENT);
}

// 4B publication via fire-and-forget atomic swap: executes at the LLC
// (memory-side), no return, no stale-buffer risk (R15-proven path).
__device__ __forceinline__ void st_pub4(float* p, float v) {
  asm volatile("global_atomic_swap %0, %1, off"
               :: "v"(p), "v"(v) : "memory");
}

__device__ __forceinline__ bool validf(float a, float b, float c, float d) {
  return __float_as_uint(a) != 0xAAAAAAAAu && __float_as_uint(b) != 0xAAAAAAAAu &&
         __float_as_uint(c) != 0xAAAAAAAAu && __float_as_uint(d) != 0xAAAAAAAAu;
}

// atomic poison-poll of one 16B granule: 4 parallel returning atomic-ORs per
// round (coherence-point reads). First round immediate; failed rounds are
// s_sleep-throttled to bound per-address serialization.
__device__ __forceinline__ fv4 apoll(float* p, int* okp) {
  unsigned* q = (unsigned*)p;
  fv4 r;
  int ok = 1;
  for (unsigned it = 0;; ++it) {
    const unsigned a = ld_coh(q + 0);
    const unsigned b = ld_coh(q + 1);
    const unsigned c = ld_coh(q + 2);
    const unsigned d = ld_coh(q + 3);
    if (a != 0xAAAAAAAAu && b != 0xAAAAAAAAu &&
        c != 0xAAAAAAAAu && d != 0xAAAAAAAAu) {
      r.x = __uint_as_float(a); r.y = __uint_as_float(b);
      r.z = __uint_as_float(c); r.w = __uint_as_float(d);
      break;
    }
    if (it > APOLL_LIMIT) { ok = 0; r.x = r.y = r.z = r.w = 0.f; break; }
    __builtin_amdgcn_s_sleep(1);
  }
  *okp = ok;
  return r;
}

// ------------- precompute PX = W_ih_e @ x_t + b_ih_e + b_hh_e -----------------
// px[(t*1024 + h)*4 + g] for gate row r = g*1024 + h.
__global__ __launch_bounds__(256) void prep_gemm(const float* __restrict__ X,
                                                 const float* __restrict__ Wih,
                                                 const float* __restrict__ bih,
                                                 const float* __restrict__ bhh,
                                                 float* __restrict__ px) {
  __shared__ float Ws[64][68];
  __shared__ float Xs[64][68];
  const int r0 = blockIdx.x * 64;
  const int t0 = blockIdx.y * 64;
  const int tid = threadIdx.x;
  const int tr = tid & 15;
  const int tc = tid >> 4;
  float acc[4][4] = {{0.f}};
  for (int k0 = 0; k0 < 512; k0 += 64) {
    __syncthreads();
    const int lr = tid >> 4;
    const int lc = (tid & 15) * 4;
#pragma unroll
    for (int rep = 0; rep < 4; rep++) {
      const int row = lr + rep * 16;
      const float4 wv = *(const float4*)&Wih[(size_t)(r0 + row) * 512 + k0 + lc];
      Ws[lc + 0][row] = wv.x; Ws[lc + 1][row] = wv.y;
      Ws[lc + 2][row] = wv.z; Ws[lc + 3][row] = wv.w;
      const float4 xv = *(const float4*)&X[(size_t)(t0 + row) * 512 + k0 + lc];
      Xs[row][lc + 0] = xv.x; Xs[row][lc + 1] = xv.y;
      Xs[row][lc + 2] = xv.z; Xs[row][lc + 3] = xv.w;
    }
    __syncthreads();
    for (int kk = 0; kk < 64; kk++) {
      float a[4], x[4];
#pragma unroll
      for (int i = 0; i < 4; i++) a[i] = Ws[kk][tr * 4 + i];
#pragma unroll
      for (int j = 0; j < 4; j++) x[j] = Xs[tc * 4 + j][kk];
#pragma unroll
      for (int i = 0; i < 4; i++)
#pragma unroll
        for (int j = 0; j < 4; j++) acc[i][j] += a[i] * x[j];
    }
  }
#pragma unroll
  for (int i = 0; i < 4; i++) {
    const int r = r0 + tr * 4 + i;
    const int g = r >> 10, h = r & 1023;
    const float bsum = bih[r] + bhh[r];
#pragma unroll
    for (int j = 0; j < 4; j++) {
      const int t = t0 + tc * 4 + j;
      px[((size_t)t * 1024 + h) * 4 + g] = acc[i][j] + bsum;
    }
  }
}

// ------------------------------ persistent kernel -----------------------------
// 512 threads: wave w (0..7) owns gate g=w>>1, h-rows j=(w&1)*4+ri (ri=lane&3);
// lane s16=lane>>2 covers K in [s16*64, s16*64+64) as 16 float4 (rot by s16).
__global__ __launch_bounds__(512, 1) void lstm_persist(
    const float* __restrict__ Whhe, const float* __restrict__ Wattn,
    const float* __restrict__ battn, const float* __restrict__ Wihd,
    const float* __restrict__ Whhd, const float* __restrict__ bihd,
    const float* __restrict__ bhhd, const float* __restrict__ Wout,
    const float* __restrict__ bout, const float* __restrict__ px,
    float* ehbuf, float* dhbuf, float* out) {
  __shared__ float4 xbuf[256];   // eh copy (both groups)
  __shared__ float4 dbuf[256];   // dh copy (decoder)
  __shared__ float  aw[512];     // softmax state (decoder)
  __shared__ float  GA[32];      // gate sums (enc ge / dec g1)
  __shared__ float  GB[32];      // dec g2
  __shared__ float  bd[32];      // decoder bias
  __shared__ float  redE[4];     // energy (eh part)
  __shared__ float  redE2[4];    // energy (dh part)
  __shared__ float  red[8];      // softmax sums (8 waves)
  __shared__ float  red2[4];     // out-dot reduce
  __shared__ int    sbad;

  const int b    = blockIdx.x;
  const int tid  = threadIdx.x;
  const int w    = tid >> 6;
  const int lane = tid & 63;
  const int ri   = lane & 3;    // row-in-wave
  const int s16  = lane >> 2;   // K-segment 0..15 (64 floats)
  const int g    = w >> 1;      // gate index
  const int j    = ((w & 1) << 2) + ri;  // h-row within block's 8

  if (b < ENC_BLK) {
    // =========================== encoder group ===============================
    const int e = b;
    const int r = (g << 10) + (e << 3) + j;  // owned gate row
    float4 we[16];
#pragma unroll
    for (int k = 0; k < 16; k++) {
      const int m = (k + s16) & 15;
      we[k] = *(const float4*)&Whhe[(size_t)r * 1024 + s16 * 64 + m * 4];
    }
    if (tid < 256) xbuf[tid] = make_float4(0.f, 0.f, 0.f, 0.f);
    if (tid == 0) sbad = 0;
    float ec = 0.f;  // cell state (tid<8)
    __syncthreads();

    for (int t = 0; t < T_STEPS; t++) {
      float ge = 0.f;
#pragma unroll
      for (int k = 0; k < 16; k++) {
        const int m = (k + s16) & 15;
        const float4 x = xbuf[s16 * 16 + m];
        ge += we[k].x * x.x + we[k].y * x.y + we[k].z * x.z + we[k].w * x.w;
      }
      if (s16 == 0) ge += px[((size_t)t * 1024 + (e << 3) + j) * 4 + g];
      ge += __shfl_xor(ge, 4, 64);
      ge += __shfl_xor(ge, 8, 64);
      ge += __shfl_xor(ge, 16, 64);
      ge += __shfl_xor(ge, 32, 64);
      if (lane < 4) GA[w * 4 + lane] = ge;  // GA[g*8+j]
      __syncthreads();  // S1
      if (tid < 8) {
        const float gi = GA[tid], gf = GA[8 + tid], gg = GA[16 + tid], go = GA[24 + tid];
        const float c = sigf(gf) * ec + sigf(gi) * tanhf(gg);
        ec = c;
        const float h = sigf(go) * tanhf(c);
        st_pub4(&ehbuf[(size_t)t * 1024 + (e << 3) + tid], h);  // LLC-executed
      }
      int ok = 1;
      if (tid < 256) {
        const fv4 ev = apoll(&ehbuf[(size_t)t * 1024 + tid * 4], &ok);
        xbuf[tid] = make_float4(ev.x, ev.y, ev.z, ev.w);
      }
      if (!ok) sbad = 1;
      __syncthreads();  // S2
      if (sbad) break;
    }
  } else {
    // =========================== decoder group ===============================
    const int d = b - ENC_BLK;
    const int r = (g << 10) + (d << 3) + j;  // owned gate row
    float4 w1[16], wr[16];
#pragma unroll
    for (int k = 0; k < 16; k++) {
      const int m = (k + s16) & 15;
      w1[k] = *(const float4*)&Wihd[(size_t)r * 2048 + s16 * 64 + m * 4];
      const float4 a = *(const float4*)&Wihd[(size_t)r * 2048 + 1024 + s16 * 64 + m * 4];
      const float4 c = *(const float4*)&Whhd[(size_t)r * 1024 + s16 * 64 + m * 4];
      wr[k] = make_float4(a.x + c.x, a.y + c.y, a.z + c.z, a.w + c.w);
    }
    if (tid < 32) {
      const int gg2 = tid >> 3, jj2 = tid & 7;
      bd[tid] = bihd[(gg2 << 10) + (d << 3) + jj2] + bhhd[(gg2 << 10) + (d << 3) + jj2];
    }
    aw[tid] = 0.f;
    if (tid < 256) {
      xbuf[tid] = make_float4(0.f, 0.f, 0.f, 0.f);
      dbuf[tid] = make_float4(0.f, 0.f, 0.f, 0.f);
    }
    if (tid == 0) sbad = 0;
    float dc = 0.f;  // cell state (tid<8)
    float4 wo = make_float4(0.f, 0.f, 0.f, 0.f);
    if (tid < 256) wo = *(const float4*)&Wout[tid * 4];
    const float boutv = bout[0];
    __syncthreads();

    // loop-carried eh(t) speculative samples: coherence-point reads issued at
    // the end of iteration t-1 (in flight across the back edge).
    float es0 = 0.f, es1 = 0.f, es2 = 0.f, es3 = 0.f;
    if (tid < 256) {
      unsigned* pe = (unsigned*)&ehbuf[(size_t)tid * 4];
      es0 = __uint_as_float(ld_coh(pe + 0));
      es1 = __uint_as_float(ld_coh(pe + 1));
      es2 = __uint_as_float(ld_coh(pe + 2));
      es3 = __uint_as_float(ld_coh(pe + 3));
    }

    bool failed = false;
    for (int t = 0; t < T_STEPS; t++) {
      // --- softmax partials over stale aw (overlaps in-flight eh samples) ---
      const float battn_t = battn[t];
      const float ex0 = expf(aw[tid]);  // aw in [0,1]: exp safe, no max needed
      float so = (tid == t) ? 0.f : ex0;
#pragma unroll
      for (int mk = 1; mk <= 32; mk <<= 1) so += __shfl_xor(so, mk, 64);
      if (lane == 0) red[w] = so;

      // --- consume eh(t): spec-hit or atomic-poll fallback ---
      float4 wae = make_float4(0.f, 0.f, 0.f, 0.f);
      float4 wad = make_float4(0.f, 0.f, 0.f, 0.f);
      float epe = 0.f;
      int ok1 = 1;
      if (tid < 256) {
        wae = *(const float4*)&Wattn[(size_t)t * 2048 + tid * 4];
        wad = *(const float4*)&Wattn[(size_t)t * 2048 + 1024 + tid * 4];
        fv4 ev;
        if (validf(es0, es1, es2, es3)) {
          ev.x = es0; ev.y = es1; ev.z = es2; ev.w = es3;
        } else {
          ev = apoll(&ehbuf[(size_t)t * 1024 + tid * 4], &ok1);
        }
        epe = wae.x * ev.x + wae.y * ev.y + wae.z * ev.z + wae.w * ev.w;
        xbuf[tid] = make_float4(ev.x, ev.y, ev.z, ev.w);
      }
      if (!ok1) sbad = 1;
#pragma unroll
      for (int mk = 1; mk <= 32; mk <<= 1) epe += __shfl_xor(epe, mk, 64);
      if (lane == 0 && w < 4) redE[w] = epe;
      __syncthreads();  // B1
      if (sbad) { failed = true; break; }

      // --- issue dh(t-1) coherence-point samples; g1 matvec covers the RTT ---
      float ds0 = 0.f, ds1 = 0.f, ds2 = 0.f, ds3 = 0.f;
      if (t > 0 && tid < 256) {
        unsigned* pd = (unsigned*)&dhbuf[(size_t)(t - 1) * 1024 + tid * 4];
        ds0 = __uint_as_float(ld_coh(pd + 0));
        ds1 = __uint_as_float(ld_coh(pd + 1));
        ds2 = __uint_as_float(ld_coh(pd + 2));
        ds3 = __uint_as_float(ld_coh(pd + 3));
      }

      float g1 = 0.f;
#pragma unroll
      for (int k = 0; k < 16; k++) {
        const int m = (k + s16) & 15;
        const float4 x = xbuf[s16 * 16 + m];
        g1 += w1[k].x * x.x + w1[k].y * x.y + w1[k].z * x.z + w1[k].w * x.w;
      }
      g1 += __shfl_xor(g1, 4, 64);
      g1 += __shfl_xor(g1, 8, 64);
      g1 += __shfl_xor(g1, 16, 64);
      g1 += __shfl_xor(g1, 32, 64);
      if (lane < 4) GA[w * 4 + lane] = g1;

      // --- consume dh(t-1): the recurrence-critical wait ---
      float epd = 0.f;
      int ok2 = 1;
      if (t > 0 && tid < 256) {
        fv4 dv;
        if (validf(ds0, ds1, ds2, ds3)) {
          dv.x = ds0; dv.y = ds1; dv.z = ds2; dv.w = ds3;
        } else {
          dv = apoll(&dhbuf[(size_t)(t - 1) * 1024 + tid * 4], &ok2);
        }
        epd = wad.x * dv.x + wad.y * dv.y + wad.z * dv.z + wad.w * dv.w;
        dbuf[tid] = make_float4(dv.x, dv.y, dv.z, dv.w);
      }
      if (!ok2) sbad = 1;
#pragma unroll
      for (int mk = 1; mk <= 32; mk <<= 1) epd += __shfl_xor(epd, mk, 64);
      if (lane == 0 && w < 4) redE2[w] = epd;
      __syncthreads();  // B2
      if (sbad) { failed = true; break; }

      // --- g2 = (Wihd[:,H:]+Whhd) @ dh(t-1) ---
      float g2 = 0.f;
#pragma unroll
      for (int k = 0; k < 16; k++) {
        const int m = (k + s16) & 15;
        const float4 dd = dbuf[s16 * 16 + m];
        g2 += wr[k].x * dd.x + wr[k].y * dd.y + wr[k].z * dd.z + wr[k].w * dd.w;
      }
      g2 += __shfl_xor(g2, 4, 64);
      g2 += __shfl_xor(g2, 8, 64);
      g2 += __shfl_xor(g2, 16, 64);
      g2 += __shfl_xor(g2, 32, 64);
      if (lane < 4) GB[w * 4 + lane] = g2;

      // --- softmax finish (all threads redundantly) + aw update ---
      const float e_t = redE[0] + redE[1] + redE[2] + redE[3] +
                        redE2[0] + redE2[1] + redE2[2] + redE2[3] + battn_t;
      const float exden = expf(e_t);
      const float inv = 1.f / (red[0] + red[1] + red[2] + red[3] +
                               red[4] + red[5] + red[6] + red[7] + exden);
      const float awt = exden * inv;
      aw[tid] = ((tid == t) ? exden : ex0) * inv;
      __syncthreads();  // S3 (GA/GB ready)

      // --- decoder cell (tid<8) + LLC-executed publication ---
      if (tid < 8) {
        const float gi = awt * GA[tid]      + GB[tid]      + bd[tid];
        const float gf = awt * GA[8 + tid]  + GB[8 + tid]  + bd[8 + tid];
        const float gg = awt * GA[16 + tid] + GB[16 + tid] + bd[16 + tid];
        const float go = awt * GA[24 + tid] + GB[24 + tid] + bd[24 + tid];
        const float c = sigf(gf) * dc + sigf(gi) * tanhf(gg);
        dc = c;
        const float h = sigf(go) * tanhf(c);
        st_pub4(&dhbuf[(size_t)t * 1024 + (d << 3) + tid], h);
      }

      // --- issue eh(t+1) coherence-point samples (in flight across back edge) ---
      if (tid < 256) {
        const int tn = (t + 1 < T_STEPS) ? (t + 1) : t;  // last iter: harmless
        unsigned* pe = (unsigned*)&ehbuf[(size_t)tn * 1024 + tid * 4];
        es0 = __uint_as_float(ld_coh(pe + 0));
        es1 = __uint_as_float(ld_coh(pe + 1));
        es2 = __uint_as_float(ld_coh(pe + 2));
        es3 = __uint_as_float(ld_coh(pe + 3));
      }
    }

    // --- epilogue: out[t] = W_out·dh(t) + b_out, 4 t-values per block ---
    if (!failed) {
#pragma unroll
      for (int i = 0; i < 4; i++) {
        const int t = d * 4 + i;
        float op = 0.f;
        int ok = 1;
        if (tid < 256) {
          const fv4 dv = apoll(&dhbuf[(size_t)t * 1024 + tid * 4], &ok);
          op = wo.x * dv.x + wo.y * dv.y + wo.z * dv.z + wo.w * dv.w;
        }
        if (!ok) break;
#pragma unroll
        for (int mk = 1; mk <= 32; mk <<= 1) op += __shfl_xor(op, mk, 64);
        if (lane == 0 && w < 4) red2[w] = op;
        __syncthreads();
        if (tid == 0) out[t] = red2[0] + red2[1] + red2[2] + red2[3] + boutv;
        __syncthreads();
      }
    }
  }
}

// ---------------------------------- launch ------------------------------------
extern "C" void kernel_launch(void* const* d_in, const int* in_sizes, int n_in,
                              void* d_out, int out_size, void* d_ws, size_t ws_size,
                              hipStream_t stream) {
  const float* X     = (const float*)d_in[0];
  const float* Wihe  = (const float*)d_in[2];
  const float* Whhe  = (const float*)d_in[3];
  const float* bihe  = (const float*)d_in[4];
  const float* bhhe  = (const float*)d_in[5];
  const float* Wattn = (const float*)d_in[6];
  const float* battn = (const float*)d_in[7];
  const float* Wihd  = (const float*)d_in[8];
  const float* Whhd  = (const float*)d_in[9];
  const float* bihd  = (const float*)d_in[10];
  const float* bhhd  = (const float*)d_in[11];
  const float* Wo    = (const float*)d_in[12];
  const float* bo    = (const float*)d_in[13];
  float* out = (float*)d_out;

  float* ws    = (float*)d_ws;
  float* px    = ws;                                  // 512*1024*4 floats (8 MB)
  float* ehbuf = px + (size_t)T_STEPS * 1024 * 4;     // 512*1024 (2 MB)
  float* dhbuf = ehbuf + (size_t)T_STEPS * 1024;      // 512*1024 (2 MB)
  const size_t need = ((size_t)T_STEPS * 1024 * 6) * sizeof(float);
  if (ws_size < need) return;

  prep_gemm<<<dim3(64, 8), 256, 0, stream>>>(X, Wihe, bihe, bhhe, px);
  lstm_persist<<<NBLK, NTHR, 0, stream>>>(
      Whhe, Wattn, battn, Wihd, Whhd, bihd, bhhd, Wo, bo, px, ehbuf, dhbuf, out);
}

// Round 9
// 1769.635 us; speedup vs baseline: 1.0335x; 1.0335x over previous
//
#include <hip/hip_runtime.h>
#include <math.h>

// TransformersLSTM: T=512, I=512, H=1024, L=512, O=1.
// Split-grid persistent kernel: blocks 0..127 encoder, 128..255 decoder.
// R21 = R13 (best-measured variant of the session: 1776.9us e2e, 1681us
// counter-min). FINAL: the handoff latency V~2.5-2.6us is intrinsic
// cross-XCD rendezvous latency on MI355X. Falsification matrix (R13-R20):
//   - poller population 65536 -> 128 (R13/R18): null
//   - producer path: write-through store vs LLC-executed atomic (R15/R20): null
//   - serialized discovery: flags (R16), timed gather (R17), sentinel+one-shot
//     (R18): all WORSE than continuous parallel polling
//   - load scope bits sc1 (R19), atomic-RMW coherence-point reads (R20): null
// Register-file arithmetic forbids the only escape (single-XCD ring):
// encoder weights (16MB, VGPR-resident across 128 blocks) equal one XCD's
// entire VGPR file; decoder needs 32MB. Rings must span >=2 XCDs -> every
// step pays V. Per-step floor = V + compute ~= 3.2us; enc/dec overlap is
// already total (R14: split phases SUM to the combined time). 512 steps ->
// ~1.7ms. The kernel is at its structural latency floor; counters (VALUBusy
// 22%, HBM 0.85%, Mfma 0) reflect dependency-bound idling, not slack.

#define T_STEPS 512
#define ENC_BLK 128
#define NBLK    256
#define NTHR    512
#define POLL_LIMIT 30000u

typedef float fv4 __attribute__((ext_vector_type(4)));

__device__ __forceinline__ float sigf(float x) { return 1.0f / (1.0f + expf(-x)); }

// relaxed agent-scope load: device-coherent dword load, compiler-scheduled.
__device__ __forceinline__ float ld_f(const float* p) {
  return __hip_atomic_load(p, __ATOMIC_RELAXED, __HIP_MEMORY_SCOPE_AGENT);
}

// 4B cache-bypass store (to LLC); issued by one wave, fully coalesced.
__device__ __forceinline__ void st_bypass4(float* p, float v) {
  asm volatile("global_store_dword %0, %1, off sc0 sc1"
               :: "v"(p), "v"(v) : "memory");
}

__device__ __forceinline__ bool valid4(fv4 v) {
  return __float_as_uint(v.x) != 0xAAAAAAAAu && __float_as_uint(v.y) != 0xAAAAAAAAu &&
         __float_as_uint(v.z) != 0xAAAAAAAAu && __float_as_uint(v.w) != 0xAAAAAAAAu;
}
__device__ __forceinline__ bool validf(float a, float b, float c, float d) {
  return __float_as_uint(a) != 0xAAAAAAAAu && __float_as_uint(b) != 0xAAAAAAAAu &&
         __float_as_uint(c) != 0xAAAAAAAAu && __float_as_uint(d) != 0xAAAAAAAAu;
}

// 2-deep pipelined poison-poll of one 16B granule (sliding vmcnt(1) window).
// Self-contained asm (all waits internal) -- sound. SLP>0 adds s_sleep backoff
// per retry iteration (first two checks immediate: fast discovery, throttled
// steady-state request rate).
template <int SLP>
__device__ __forceinline__ fv4 poll2(const float* p, int* okp) {
  fv4 a, b;
  int ok = 1;
  asm volatile("global_load_dwordx4 %0, %1, off sc0 sc1" : "=v"(a) : "v"(p) : "memory");
  for (unsigned it = 0;; ++it) {
    asm volatile("global_load_dwordx4 %0, %1, off sc0 sc1" : "=v"(b) : "v"(p) : "memory");
    asm volatile("s_waitcnt vmcnt(1)" : "+v"(a) :: "memory");  // oldest (a) done
    if (valid4(a)) { asm volatile("s_waitcnt vmcnt(0)" ::: "memory"); break; }
    asm volatile("global_load_dwordx4 %0, %1, off sc0 sc1" : "=v"(a) : "v"(p) : "memory");
    asm volatile("s_waitcnt vmcnt(1)" : "+v"(b) :: "memory");  // oldest (b) done
    if (valid4(b)) { asm volatile("s_waitcnt vmcnt(0)" ::: "memory"); a = b; break; }
    if (it > POLL_LIMIT) { ok = 0; asm volatile("s_waitcnt vmcnt(0)" ::: "memory"); break; }
    if (SLP) __builtin_amdgcn_s_sleep(SLP);
  }
  *okp = ok;
  return a;
}

// one-shot 16B device-coherent load (no spin).
__device__ __forceinline__ fv4 ld_once4(const float* p) {
  fv4 a;
  asm volatile("global_load_dwordx4 %0, %1, off sc0 sc1" : "=v"(a) : "v"(p) : "memory");
  asm volatile("s_waitcnt vmcnt(0)" : "+v"(a) :: "memory");
  return a;
}

// ------------- precompute PX = W_ih_e @ x_t + b_ih_e + b_hh_e -----------------
// px[(t*1024 + h)*4 + g] for gate row r = g*1024 + h.
__global__ __launch_bounds__(256) void prep_gemm(const float* __restrict__ X,
                                                 const float* __restrict__ Wih,
                                                 const float* __restrict__ bih,
                                                 const float* __restrict__ bhh,
                                                 float* __restrict__ px) {
  __shared__ float Ws[64][68];
  __shared__ float Xs[64][68];
  const int r0 = blockIdx.x * 64;
  const int t0 = blockIdx.y * 64;
  const int tid = threadIdx.x;
  const int tr = tid & 15;
  const int tc = tid >> 4;
  float acc[4][4] = {{0.f}};
  for (int k0 = 0; k0 < 512; k0 += 64) {
    __syncthreads();
    const int lr = tid >> 4;
    const int lc = (tid & 15) * 4;
#pragma unroll
    for (int rep = 0; rep < 4; rep++) {
      const int row = lr + rep * 16;
      const float4 wv = *(const float4*)&Wih[(size_t)(r0 + row) * 512 + k0 + lc];
      Ws[lc + 0][row] = wv.x; Ws[lc + 1][row] = wv.y;
      Ws[lc + 2][row] = wv.z; Ws[lc + 3][row] = wv.w;
      const float4 xv = *(const float4*)&X[(size_t)(t0 + row) * 512 + k0 + lc];
      Xs[row][lc + 0] = xv.x; Xs[row][lc + 1] = xv.y;
      Xs[row][lc + 2] = xv.z; Xs[row][lc + 3] = xv.w;
    }
    __syncthreads();
    for (int kk = 0; kk < 64; kk++) {
      float a[4], x[4];
#pragma unroll
      for (int i = 0; i < 4; i++) a[i] = Ws[kk][tr * 4 + i];
#pragma unroll
      for (int j = 0; j < 4; j++) x[j] = Xs[tc * 4 + j][kk];
#pragma unroll
      for (int i = 0; i < 4; i++)
#pragma unroll
        for (int j = 0; j < 4; j++) acc[i][j] += a[i] * x[j];
    }
  }
#pragma unroll
  for (int i = 0; i < 4; i++) {
    const int r = r0 + tr * 4 + i;
    const int g = r >> 10, h = r & 1023;
    const float bsum = bih[r] + bhh[r];
#pragma unroll
    for (int j = 0; j < 4; j++) {
      const int t = t0 + tc * 4 + j;
      px[((size_t)t * 1024 + h) * 4 + g] = acc[i][j] + bsum;
    }
  }
}

// ------------------------------ persistent kernel -----------------------------
// 512 threads: wave w (0..7) owns gate g=w>>1, h-rows j=(w&1)*4+ri (ri=lane&3);
// lane s16=lane>>2 covers K in [s16*64, s16*64+64) as 16 float4 (rot by s16).
__global__ __launch_bounds__(512, 1) void lstm_persist(
    const float* __restrict__ Whhe, const float* __restrict__ Wattn,
    const float* __restrict__ battn, const float* __restrict__ Wihd,
    const float* __restrict__ Whhd, const float* __restrict__ bihd,
    const float* __restrict__ bhhd, const float* __restrict__ Wout,
    const float* __restrict__ bout, const float* __restrict__ px,
    float* ehbuf, float* dhbuf, float* out) {
  __shared__ float4 xbuf[256];   // eh copy (both groups)
  __shared__ float4 dbuf[256];   // dh copy (decoder)
  __shared__ float  aw[512];     // softmax state (decoder)
  __shared__ float  GA[32];      // gate sums (enc ge / dec g1)
  __shared__ float  GB[32];      // dec g2
  __shared__ float  bd[32];      // decoder bias
  __shared__ float  redE[4];     // energy (eh part)
  __shared__ float  redE2[4];    // energy (dh part)
  __shared__ float  red[8];      // softmax sums (8 waves)
  __shared__ float  red2[4];     // out-dot reduce
  __shared__ int    sbad;

  const int b    = blockIdx.x;
  const int tid  = threadIdx.x;
  const int w    = tid >> 6;
  const int lane = tid & 63;
  const int ri   = lane & 3;    // row-in-wave
  const int s16  = lane >> 2;   // K-segment 0..15 (64 floats)
  const int g    = w >> 1;      // gate index
  const int j    = ((w & 1) << 2) + ri;  // h-row within block's 8

  if (b < ENC_BLK) {
    // =========================== encoder group ===============================
    const int e = b;
    const int r = (g << 10) + (e << 3) + j;  // owned gate row
    float4 we[16];
#pragma unroll
    for (int k = 0; k < 16; k++) {
      const int m = (k + s16) & 15;
      we[k] = *(const float4*)&Whhe[(size_t)r * 1024 + s16 * 64 + m * 4];
    }
    if (tid < 256) xbuf[tid] = make_float4(0.f, 0.f, 0.f, 0.f);
    if (tid == 0) sbad = 0;
    float ec = 0.f;  // cell state (tid<8)
    __syncthreads();

    for (int t = 0; t < T_STEPS; t++) {
      float ge = 0.f;
#pragma unroll
      for (int k = 0; k < 16; k++) {
        const int m = (k + s16) & 15;
        const float4 x = xbuf[s16 * 16 + m];
        ge += we[k].x * x.x + we[k].y * x.y + we[k].z * x.z + we[k].w * x.w;
      }
      if (s16 == 0) ge += px[((size_t)t * 1024 + (e << 3) + j) * 4 + g];
      ge += __shfl_xor(ge, 4, 64);
      ge += __shfl_xor(ge, 8, 64);
      ge += __shfl_xor(ge, 16, 64);
      ge += __shfl_xor(ge, 32, 64);
      if (lane < 4) GA[w * 4 + lane] = ge;  // GA[g*8+j]
      __syncthreads();  // S1
      if (tid < 8) {
        const float gi = GA[tid], gf = GA[8 + tid], gg = GA[16 + tid], go = GA[24 + tid];
        const float c = sigf(gf) * ec + sigf(gi) * tanhf(gg);
        ec = c;
        const float h = sigf(go) * tanhf(c);
        st_bypass4(&ehbuf[(size_t)t * 1024 + (e << 3) + tid], h);  // coalesced 32B
      }
      // sentinels: 16 idle wave-4 threads sample 16 spread producers'
      // granules (rotated per block: ~8 pollers per LLC line chip-wide).
      if (tid >= 256 && tid < 272) {
        int oks;
        const int sg = ((e << 1) + ((tid - 256) << 4)) & 255;
        (void)poll2<0>(&ehbuf[(size_t)t * 1024 + sg * 4], &oks);
      }
      __syncthreads();  // Ssent: sampled producers done -> frontier ~complete
      int ok = 1;
      if (tid < 256) {
        fv4 ev = ld_once4(&ehbuf[(size_t)t * 1024 + tid * 4]);
        if (!valid4(ev)) ev = poll2<0>(&ehbuf[(size_t)t * 1024 + tid * 4], &ok);
        xbuf[tid] = make_float4(ev.x, ev.y, ev.z, ev.w);
      }
      if (!ok) sbad = 1;
      __syncthreads();  // S2
      if (sbad) break;
    }
  } else {
    // =========================== decoder group ===============================
    const int d = b - ENC_BLK;
    const int r = (g << 10) + (d << 3) + j;  // owned gate row
    float4 w1[16], wr[16];
#pragma unroll
    for (int k = 0; k < 16; k++) {
      const int m = (k + s16) & 15;
      w1[k] = *(const float4*)&Wihd[(size_t)r * 2048 + s16 * 64 + m * 4];
      const float4 a = *(const float4*)&Wihd[(size_t)r * 2048 + 1024 + s16 * 64 + m * 4];
      const float4 c = *(const float4*)&Whhd[(size_t)r * 1024 + s16 * 64 + m * 4];
      wr[k] = make_float4(a.x + c.x, a.y + c.y, a.z + c.z, a.w + c.w);
    }
    if (tid < 32) {
      const int gg2 = tid >> 3, jj2 = tid & 7;
      bd[tid] = bihd[(gg2 << 10) + (d << 3) + jj2] + bhhd[(gg2 << 10) + (d << 3) + jj2];
    }
    aw[tid] = 0.f;
    if (tid < 256) {
      xbuf[tid] = make_float4(0.f, 0.f, 0.f, 0.f);
      dbuf[tid] = make_float4(0.f, 0.f, 0.f, 0.f);
    }
    if (tid == 0) sbad = 0;
    float dc = 0.f;  // cell state (tid<8)
    float4 wo = make_float4(0.f, 0.f, 0.f, 0.f);
    if (tid < 256) wo = *(const float4*)&Wout[tid * 4];
    const float boutv = bout[0];
    __syncthreads();

    // loop-carried eh(t) speculative sample (compiler-managed in-flight).
    float es0 = 0.f, es1 = 0.f, es2 = 0.f, es3 = 0.f;
    if (tid < 256) {
      const float* pe = &ehbuf[(size_t)tid * 4];
      es0 = ld_f(pe + 0); es1 = ld_f(pe + 1); es2 = ld_f(pe + 2); es3 = ld_f(pe + 3);
    }

    bool failed = false;
    for (int t = 0; t < T_STEPS; t++) {
      // --- softmax partials over stale aw (overlaps in-flight eh samples) ---
      const float battn_t = battn[t];
      const float ex0 = expf(aw[tid]);  // aw in [0,1]: exp safe, no max needed
      float so = (tid == t) ? 0.f : ex0;
#pragma unroll
      for (int mk = 1; mk <= 32; mk <<= 1) so += __shfl_xor(so, mk, 64);
      if (lane == 0) red[w] = so;

      // --- consume eh(t): samples issued last iteration; fallback has sleep
      // backoff so a caught-up decoder self-throttles back into the lag
      // regime (samples valid -> zero frontier polls) ---
      float4 wae = make_float4(0.f, 0.f, 0.f, 0.f);
      float4 wad = make_float4(0.f, 0.f, 0.f, 0.f);
      float epe = 0.f;
      int ok1 = 1;
      if (tid < 256) {
        wae = *(const float4*)&Wattn[(size_t)t * 2048 + tid * 4];
        wad = *(const float4*)&Wattn[(size_t)t * 2048 + 1024 + tid * 4];
        fv4 ev;
        if (validf(es0, es1, es2, es3)) {
          ev.x = es0; ev.y = es1; ev.z = es2; ev.w = es3;
        } else {
          ev = poll2<8>(&ehbuf[(size_t)t * 1024 + tid * 4], &ok1);
        }
        epe = wae.x * ev.x + wae.y * ev.y + wae.z * ev.z + wae.w * ev.w;
        xbuf[tid] = make_float4(ev.x, ev.y, ev.z, ev.w);
      }
      if (!ok1) sbad = 1;
#pragma unroll
      for (int mk = 1; mk <= 32; mk <<= 1) epe += __shfl_xor(epe, mk, 64);
      if (lane == 0 && w < 4) redE[w] = epe;
      __syncthreads();  // B1
      if (sbad) { failed = true; break; }

      // --- issue dh(t-1) speculative samples; g1 matvec covers the RTT ---
      float ds0 = 0.f, ds1 = 0.f, ds2 = 0.f, ds3 = 0.f;
      if (t > 0 && tid < 256) {
        const float* pd = &dhbuf[(size_t)(t - 1) * 1024 + tid * 4];
        ds0 = ld_f(pd + 0); ds1 = ld_f(pd + 1); ds2 = ld_f(pd + 2); ds3 = ld_f(pd + 3);
      }

      float g1 = 0.f;
#pragma unroll
      for (int k = 0; k < 16; k++) {
        const int m = (k + s16) & 15;
        const float4 x = xbuf[s16 * 16 + m];
        g1 += w1[k].x * x.x + w1[k].y * x.y + w1[k].z * x.z + w1[k].w * x.w;
      }
      g1 += __shfl_xor(g1, 4, 64);
      g1 += __shfl_xor(g1, 8, 64);
      g1 += __shfl_xor(g1, 16, 64);
      g1 += __shfl_xor(g1, 32, 64);
      if (lane < 4) GA[w * 4 + lane] = g1;

      // --- consume dh(t-1): the recurrence-critical wait ---
      float epd = 0.f;
      int ok2 = 1;
      if (t > 0 && tid < 256) {
        fv4 dv;
        if (validf(ds0, ds1, ds2, ds3)) {
          dv.x = ds0; dv.y = ds1; dv.z = ds2; dv.w = ds3;
        } else {
          dv = poll2<4>(&dhbuf[(size_t)(t - 1) * 1024 + tid * 4], &ok2);
        }
        epd = wad.x * dv.x + wad.y * dv.y + wad.z * dv.z + wad.w * dv.w;
        dbuf[tid] = make_float4(dv.x, dv.y, dv.z, dv.w);
      }
      if (!ok2) sbad = 1;
#pragma unroll
      for (int mk = 1; mk <= 32; mk <<= 1) epd += __shfl_xor(epd, mk, 64);
      if (lane == 0 && w < 4) redE2[w] = epd;
      __syncthreads();  // B2
      if (sbad) { failed = true; break; }

      // --- g2 = (Wihd[:,H:]+Whhd) @ dh(t-1) ---
      float g2 = 0.f;
#pragma unroll
      for (int k = 0; k < 16; k++) {
        const int m = (k + s16) & 15;
        const float4 dd = dbuf[s16 * 16 + m];
        g2 += wr[k].x * dd.x + wr[k].y * dd.y + wr[k].z * dd.z + wr[k].w * dd.w;
      }
      g2 += __shfl_xor(g2, 4, 64);
      g2 += __shfl_xor(g2, 8, 64);
      g2 += __shfl_xor(g2, 16, 64);
      g2 += __shfl_xor(g2, 32, 64);
      if (lane < 4) GB[w * 4 + lane] = g2;

      // --- softmax finish (all threads redundantly) + aw update ---
      const float e_t = redE[0] + redE[1] + redE[2] + redE[3] +
                        redE2[0] + redE2[1] + redE2[2] + redE2[3] + battn_t;
      const float exden = expf(e_t);
      const float inv = 1.f / (red[0] + red[1] + red[2] + red[3] +
                               red[4] + red[5] + red[6] + red[7] + exden);
      const float awt = exden * inv;
      aw[tid] = ((tid == t) ? exden : ex0) * inv;
      __syncthreads();  // S3 (GA/GB ready)

      // --- decoder cell (tid<8) + coalesced publication ---
      if (tid < 8) {
        const float gi = awt * GA[tid]      + GB[tid]      + bd[tid];
        const float gf = awt * GA[8 + tid]  + GB[8 + tid]  + bd[8 + tid];
        const float gg = awt * GA[16 + tid] + GB[16 + tid] + bd[16 + tid];
        const float go = awt * GA[24 + tid] + GB[24 + tid] + bd[24 + tid];
        const float c = sigf(gf) * dc + sigf(gi) * tanhf(gg);
        dc = c;
        const float h = sigf(go) * tanhf(c);
        st_bypass4(&dhbuf[(size_t)t * 1024 + (d << 3) + tid], h);
      }

      // --- issue eh(t+1) speculative samples (in flight across back edge) ---
      if (tid < 256) {
        const int tn = (t + 1 < T_STEPS) ? (t + 1) : t;  // last iter: harmless
        const float* pe = &ehbuf[(size_t)tn * 1024 + tid * 4];
        es0 = ld_f(pe + 0); es1 = ld_f(pe + 1); es2 = ld_f(pe + 2); es3 = ld_f(pe + 3);
      }
    }

    // --- epilogue: out[t] = W_out.dh(t) + b_out, 4 t-values per block ---
    if (!failed) {
#pragma unroll
      for (int i = 0; i < 4; i++) {
        const int t = d * 4 + i;
        float op = 0.f;
        int ok = 1;
        if (tid < 256) {
          const fv4 dv = poll2<0>(&dhbuf[(size_t)t * 1024 + tid * 4], &ok);
          op = wo.x * dv.x + wo.y * dv.y + wo.z * dv.z + wo.w * dv.w;
        }
        if (!ok) break;
#pragma unroll
        for (int mk = 1; mk <= 32; mk <<= 1) op += __shfl_xor(op, mk, 64);
        if (lane == 0 && w < 4) red2[w] = op;
        __syncthreads();
        if (tid == 0) out[t] = red2[0] + red2[1] + red2[2] + red2[3] + boutv;
        __syncthreads();
      }
    }
  }
}

// ---------------------------------- launch ------------------------------------
extern "C" void kernel_launch(void* const* d_in, const int* in_sizes, int n_in,
                              void* d_out, int out_size, void* d_ws, size_t ws_size,
                              hipStream_t stream) {
  const float* X     = (const float*)d_in[0];
  const float* Wihe  = (const float*)d_in[2];
  const float* Whhe  = (const float*)d_in[3];
  const float* bihe  = (const float*)d_in[4];
  const float* bhhe  = (const float*)d_in[5];
  const float* Wattn = (const float*)d_in[6];
  const float* battn = (const float*)d_in[7];
  const float* Wihd  = (const float*)d_in[8];
  const float* Whhd  = (const float*)d_in[9];
  const float* bihd  = (const float*)d_in[10];
  const float* bhhd  = (const float*)d_in[11];
  const float* Wo    = (const float*)d_in[12];
  const float* bo    = (const float*)d_in[13];
  float* out = (float*)d_out;

  float* ws    = (float*)d_ws;
  float* px    = ws;                                  // 512*1024*4 floats (8 MB)
  float* ehbuf = px + (size_t)T_STEPS * 1024 * 4;     // 512*1024 (2 MB)
  float* dhbuf = ehbuf + (size_t)T_STEPS * 1024;      // 512*1024 (2 MB)
  const size_t need = ((size_t)T_STEPS * 1024 * 6) * sizeof(float);
  if (ws_size < need) return;

  prep_gemm<<<dim3(64, 8), 256, 0, stream>>>(X, Wihe, bihe, bhhe, px);
  lstm_persist<<<NBLK, NTHR, 0, stream>>>(
      Whhe, Wattn, battn, Wihd, Whhd, bihd, bhhd, Wo, bo, px, ehbuf, dhbuf, out);
}